// Round 14
// baseline (383.677 us; speedup 1.0000x reference)
//
#include <hip/hip_runtime.h>
#include <cstdint>
#include <cstddef>

typedef _Float16 HT;
typedef _Float16 h8 __attribute__((ext_vector_type(8)));
typedef _Float16 h4 __attribute__((ext_vector_type(4)));
typedef float f32x4 __attribute__((ext_vector_type(4)));

constexpr int Tn  = 2048;
constexpr int Dm  = 2048;
constexpr int Hh  = 16;
constexpr int RDc = 64;
constexpr int QRc = 1536;
constexpr int KVRc= 512;
constexpr int BT  = 4096;

#define VWAIT(N) asm volatile("s_waitcnt vmcnt(" #N ")" ::: "memory")
#define SBAR()   __builtin_amdgcn_s_barrier()

__device__ __forceinline__ f32x4 mfma16(h8 a, h8 b, f32x4 c) {
    return __builtin_amdgcn_mfma_f32_16x16x32_f16(a, b, c, 0, 0, 0);
}
__device__ __forceinline__ void gload_lds16(const void* g, void* l) {
    __builtin_amdgcn_global_load_lds(
        (const __attribute__((address_space(1))) unsigned int*)g,
        (__attribute__((address_space(3))) unsigned int*)l, 16, 0, 0);
}

// ---------------------------------------------------------------------------
// Merged prep kernel: [0,256) cstab | [256,4000) wtrans x8 | [4000,8096) convx
// ---------------------------------------------------------------------------
struct PrepArgs {
    const float* s[8];
    HT* d[8];
    int K[8], N[8], start[8];
    float2* cs;
    const float* x;
    HT* x16;
};

__global__ __launch_bounds__(256)
void prep_kernel(PrepArgs p)
{
    __shared__ float Ts[64][65];
    const int bid = blockIdx.x;
    const int tid = threadIdx.x;

    if (bid < 256) {                      // cstab: 65536 entries
        const int idx = bid * 256 + tid;
        const int t = idx >> 5, i = idx & 31;
        const float ang = (float)t * exp2f(-(float)i * (13.287712379549449f / 32.f));
        p.cs[idx] = make_float2(cosf(ang), sinf(ang));
        return;
    }
    if (bid >= 4000) {                    // convx: fp32 x -> fp16 x16
        const size_t i = ((size_t)(bid - 4000) * 256 + tid) * 8;
        f32x4 a = *reinterpret_cast<const f32x4*>(p.x + i);
        f32x4 b = *reinterpret_cast<const f32x4*>(p.x + i + 4);
        h8 v;
        #pragma unroll
        for (int j = 0; j < 4; j++) { v[j] = (HT)a[j]; v[4 + j] = (HT)b[j]; }
        *reinterpret_cast<h8*>(p.x16 + i) = v;
        return;
    }
    // wtrans: src fp32 [K][N] -> dst fp16 [N][K]
    const int bx0 = bid - 256;
    int seg = 0;
    #pragma unroll
    for (int i = 1; i < 8; i++) if (bx0 >= p.start[i]) seg = i;
    const float* src = p.s[seg];
    HT* dst = p.d[seg];
    const int K = p.K[seg], N = p.N[seg];
    const int bx = bx0 - p.start[seg];
    const int nx = N >> 6;
    const int n0 = (bx % nx) * 64, k0 = (bx / nx) * 64;
    {
        const int r = tid >> 2, c0 = (tid & 3) * 16;
        const float* s = src + (size_t)(k0 + r) * N + n0 + c0;
        #pragma unroll
        for (int j = 0; j < 4; j++)
            *reinterpret_cast<f32x4*>(&Ts[r][c0 + j * 4]) = *reinterpret_cast<const f32x4*>(s + j * 4);
    }
    __syncthreads();
    {
        const int c = tid >> 2, kq = (tid & 3) * 16;
        h8 o0, o1;
        #pragma unroll
        for (int j = 0; j < 8; j++) { o0[j] = (HT)Ts[kq + j][c]; o1[j] = (HT)Ts[kq + 8 + j][c]; }
        HT* d = dst + (size_t)(n0 + c) * K + k0 + kq;
        *reinterpret_cast<h8*>(d)     = o0;
        *reinterpret_cast<h8*>(d + 8) = o1;
    }
}

// ---------------------------------------------------------------------------
// PROVEN R7 GEMM: 128x128 tile, BK=32, 2-slot dbuf, counted vmcnt(4),
// 2-bit XOR LDS swizzle both-sides, 32KB LDS (occupancy-optimal).
// EPI: 0=latent(cq|ckv|kr16-rope + out_k 16-head bcast) 1=Q(qn|qr-rope)
//      2=KV(kn+out_k|vt+out_v) 3=OUT(fp32)
// ---------------------------------------------------------------------------
template<int EPI>
__global__ __launch_bounds__(256)
void gemm16d(const HT* __restrict__ A, const HT* __restrict__ Bt, const int K,
             HT* __restrict__ o1, HT* __restrict__ o2, HT* __restrict__ o3,
             float* __restrict__ f1, float* __restrict__ f2,
             const float2* __restrict__ cstab)
{
    __shared__ HT As[2][4096];
    __shared__ HT Bs[2][4096];

    const int tid  = threadIdx.x;
    const int lane = tid & 63;
    const int l15  = lane & 15, l4 = lane >> 4;
    const int w    = tid >> 6;
    const int wr   = w >> 1, wc = w & 1;
    const int m0   = blockIdx.y * 128;
    const int n0   = blockIdx.x * 128;

    f32x4 acc[4][4] = {};
    const int nk = K >> 5;

    const int schunk = ((lane & 3) ^ ((lane >> 2) & 3) ^ ((lane >> 4) & 3)) * 8;

#define GSTAGE(as_, bs_, kt_) do {                                             \
    _Pragma("unroll")                                                          \
    for (int i_ = 0; i_ < 2; i_++) {                                           \
        const int row_ = (w * 2 + i_) * 16 + (lane >> 2);                      \
        gload_lds16(A  + (size_t)(m0 + row_) * K + (kt_) + schunk,             \
                    (as_) + (w * 2 + i_) * 512);                               \
        gload_lds16(Bt + (size_t)(n0 + row_) * K + (kt_) + schunk,             \
                    (bs_) + (w * 2 + i_) * 512);                               \
    } } while (0)

    GSTAGE(As[0], Bs[0], 0);

    const int sl = (l4 ^ (l15 & 3) ^ ((l15 >> 2) & 3)) * 8;

    for (int kt = 0; kt < nk; kt++) {
        HT* as = As[kt & 1];
        HT* bs = Bs[kt & 1];
        if (kt + 1 < nk) {
            GSTAGE(As[(kt + 1) & 1], Bs[(kt + 1) & 1], (kt + 1) * 32);
            VWAIT(4);
        } else {
            VWAIT(0);
        }
        SBAR();

        h8 af[4], bf[4];
        #pragma unroll
        for (int f = 0; f < 4; f++)
            af[f] = *reinterpret_cast<const h8*>(&as[(wr * 64 + f * 16 + l15) * 32 + sl]);
        #pragma unroll
        for (int g = 0; g < 4; g++)
            bf[g] = *reinterpret_cast<const h8*>(&bs[(wc * 64 + g * 16 + l15) * 32 + sl]);
        #pragma unroll
        for (int f = 0; f < 4; f++)
            #pragma unroll
            for (int g = 0; g < 4; g++)
                acc[f][g] = mfma16(af[f], bf[g], acc[f][g]);
        SBAR();
    }
#undef GSTAGE

    #pragma unroll
    for (int f = 0; f < 4; f++) {
        #pragma unroll
        for (int g = 0; g < 4; g++) {
            const int row = m0 + wr * 64 + f * 16 + l4 * 4;
            const int col = n0 + wc * 64 + g * 16 + l15;
            if constexpr (EPI == 3) {
                #pragma unroll
                for (int r = 0; r < 4; r++)
                    f1[(size_t)(row + r) * 2048 + col] = acc[f][g][r];
            } else if constexpr (EPI == 0) {
                if (col < 1536) {
                    #pragma unroll
                    for (int r = 0; r < 4; r++)
                        o1[(size_t)(row + r) * 1536 + col] = (HT)acc[f][g][r];
                } else if (col < 2048) {
                    #pragma unroll
                    for (int r = 0; r < 4; r++)
                        o2[(size_t)(row + r) * 512 + (col - 1536)] = (HT)acc[f][g][r];
                } else if (col < 2112) {
                    const int cc = col - 2048;
                    const int i = cc >> 1;
                    const bool odd = cc & 1;
                    #pragma unroll
                    for (int r = 0; r < 4; r++) {
                        const int rw = row + r;
                        const int t = rw & (Tn - 1);
                        const int b = rw >> 11;
                        const float2 cs = cstab[t * 32 + i];
                        const float v = acc[f][g][r];
                        const float p = __shfl_xor(v, 1);
                        const float ov = odd ? p * cs.y + v * cs.x : v * cs.x - p * cs.y;
                        o3[(size_t)rw * 64 + cc] = (HT)ov;
                        // fused kropebc: 16-head rope broadcast into out_k
                        #pragma unroll
                        for (int hh = 0; hh < Hh; hh++)
                            f1[((size_t)(b * Hh + hh) * Tn + t) * 192 + 128 + cc] = ov;
                    }
                }
            } else if constexpr (EPI == 1) {
                if (col < 2048) {
                    #pragma unroll
                    for (int r = 0; r < 4; r++)
                        o1[(size_t)(row + r) * 2048 + col] = (HT)acc[f][g][r];
                } else {
                    const int cc = col - 2048;
                    const int i = (cc & 63) >> 1;
                    const bool odd = cc & 1;
                    #pragma unroll
                    for (int r = 0; r < 4; r++) {
                        const int t = (row + r) & (Tn - 1);
                        const float2 cs = cstab[t * 32 + i];
                        const float v = acc[f][g][r];
                        const float p = __shfl_xor(v, 1);
                        const float ov = odd ? p * cs.y + v * cs.x : v * cs.x - p * cs.y;
                        o2[(size_t)(row + r) * 1024 + cc] = (HT)ov;
                    }
                }
            } else {  // EPI == 2
                if (col < 2048) {
                    const int h = col >> 7, d = col & 127;
                    #pragma unroll
                    for (int r = 0; r < 4; r++) {
                        const int rw = row + r;
                        const int b = rw >> 11, t = rw & (Tn - 1);
                        o1[(size_t)rw * 2048 + col] = (HT)acc[f][g][r];
                        f1[((size_t)(b * Hh + h) * Tn + t) * 192 + d] = acc[f][g][r];
                    }
                } else {
                    const int c2 = col - 2048;
                    const int h = c2 >> 7, d = c2 & 127;
                    const int b = row >> 11, t0 = row & (Tn - 1);
                    h4 pk;
                    #pragma unroll
                    for (int r = 0; r < 4; r++) {
                        f2[((size_t)(b * Hh + h) * Tn + t0 + r) * 128 + d] = acc[f][g][r];
                        pk[r] = (HT)acc[f][g][r];
                    }
                    *reinterpret_cast<h4*>(&o3[((size_t)(b * Hh + h) * 128 + d) * Tn + t0]) = pk;
                }
            }
        }
    }
}

// ---------------------------------------------------------------------------
__global__ __launch_bounds__(256)
void rmsnorm2_kernel(HT* __restrict__ Xa, const float* __restrict__ ga,
                     HT* __restrict__ Xb, const float* __restrict__ gb)
{
    const int which = blockIdx.y;
    HT* X = which ? Xb : Xa;
    const float* g = which ? gb : ga;
    const int N = which ? 512 : 1536;
    const int row = blockIdx.x;
    HT* x = X + (size_t)row * N;
    float ss = 0.f;
    for (int i = threadIdx.x * 8; i < N; i += 2048) {
        h8 v = *reinterpret_cast<const h8*>(&x[i]);
        #pragma unroll
        for (int j = 0; j < 8; j++) { float f = (float)v[j]; ss += f * f; }
    }
    #pragma unroll
    for (int sh = 32; sh >= 1; sh >>= 1) ss += __shfl_xor(ss, sh);
    __shared__ float red[4];
    if ((threadIdx.x & 63) == 0) red[threadIdx.x >> 6] = ss;
    __syncthreads();
    const float tot = red[0] + red[1] + red[2] + red[3];
    const float scale = rsqrtf(tot / (float)N + 1e-6f);
    for (int i = threadIdx.x * 8; i < N; i += 2048) {
        h8 v = *reinterpret_cast<const h8*>(&x[i]);
        f32x4 g0 = *reinterpret_cast<const f32x4*>(&g[i]);
        f32x4 g1 = *reinterpret_cast<const f32x4*>(&g[i + 4]);
        #pragma unroll
        for (int j = 0; j < 4; j++) { v[j]   = (HT)((float)v[j]   * scale * g0[j]);
                                      v[4+j] = (HT)((float)v[4+j] * scale * g1[j]); }
        *reinterpret_cast<h8*>(&x[i]) = v;
    }
}

// ---------------------------------------------------------------------------
// Flash attention v10b = attn10 (KBLK=32 dbuf counted-vmcnt, lean softmax)
// with the V bank-conflict fix: chunk swizzle (d>>1)&3 instead of d&3
// (both sides) -> lanes {l15,l15+4} now hit distinct banks; 4-way -> 2-way.
// ---------------------------------------------------------------------------
__global__ __launch_bounds__(256, 2)
void attn10_kernel(const HT* __restrict__ qn, const HT* __restrict__ qr,
                   const HT* __restrict__ kn, const HT* __restrict__ kr16,
                   const HT* __restrict__ vt, HT* __restrict__ ao)
{
    __shared__ HT Ks_n[2][32 * 128];   // 8KB/slot, row=256B, chunk^=(row&7)
    __shared__ HT Ks_r[2][32 * 64];    // 4KB/slot, row=128B, chunk^=(row&7)
    __shared__ HT Vs[2][128 * 32];     // 8KB/slot, row=64B,  chunk^=((d>>1)&3)
    __shared__ HT Ps[4][32][40];       // 10KB

    const int tid  = threadIdx.x;
    const int lane = tid & 63;
    const int l15  = lane & 15, l4 = lane >> 4;
    const int w    = tid >> 6;

    const int bid = blockIdx.x;          // 512
    const int j   = bid >> 5;
    const int h   = bid & 15;
    const int b   = (bid >> 4) & 1;
    const int thi = 31 - j;

    const size_t bT = (size_t)b * Tn;
    const HT* vt_h = vt + ((size_t)(b * Hh + h) * 128) * Tn;

    const int qw0 = j   * 64 + w * 16;
    const int qw1 = thi * 64 + w * 16;

    h8 aq0[6], aq1[6];
    {
        const HT sc = (HT)(0.07216878364870323f * 1.4426950408889634f); // 1/sqrt(192)*log2e
        const size_t rq0 = bT + qw0 + l15;
        const HT* pn = qn + rq0 * 2048 + h * 128 + l4 * 8;
        #pragma unroll
        for (int f = 0; f < 4; f++) aq0[f] = *reinterpret_cast<const h8*>(pn + f * 32) * sc;
        const HT* pr = qr + rq0 * 1024 + h * 64 + l4 * 8;
        aq0[4] = *reinterpret_cast<const h8*>(pr) * sc;
        aq0[5] = *reinterpret_cast<const h8*>(pr + 32) * sc;
        const size_t rq1 = bT + qw1 + l15;
        const HT* pn1 = qn + rq1 * 2048 + h * 128 + l4 * 8;
        #pragma unroll
        for (int f = 0; f < 4; f++) aq1[f] = *reinterpret_cast<const h8*>(pn1 + f * 32) * sc;
        const HT* pr1 = qr + rq1 * 1024 + h * 64 + l4 * 8;
        aq1[4] = *reinterpret_cast<const h8*>(pr1) * sc;
        aq1[5] = *reinterpret_cast<const h8*>(pr1 + 32) * sc;
    }

    f32x4 o0[8] = {}, o1[8] = {};
    float m0v[4] = {-1e30f, -1e30f, -1e30f, -1e30f};
    float m1v[4] = {-1e30f, -1e30f, -1e30f, -1e30f};
    float l0v[4] = {0.f, 0.f, 0.f, 0.f};
    float l1v[4] = {0.f, 0.f, 0.f, 0.f};

// 5 gload_lds chunks per wave: 2 K-nope, 1 K-rope, 2 V
#define STAGE(sl_, kb_) do {                                                    \
    _Pragma("unroll")                                                           \
    for (int jj = 0; jj < 2; jj++) {                                            \
        const int cc = w * 2 + jj;                                              \
        const int r_ = cc * 4 + (lane >> 4);                                    \
        const int cl = (l15 & 8) | ((l15 & 7) ^ (r_ & 7));                      \
        gload_lds16(kn + (bT + (kb_) + r_) * 2048 + h * 128 + cl * 8,           \
                    &Ks_n[sl_][cc * 512]);                                      \
    }                                                                           \
    {                                                                           \
        const int r_ = w * 8 + (lane >> 3);                                     \
        const int cl = (lane & 7) ^ (r_ & 7);                                   \
        gload_lds16(kr16 + (bT + (kb_) + r_) * 64 + cl * 8,                     \
                    &Ks_r[sl_][w * 512]);                                       \
    }                                                                           \
    _Pragma("unroll")                                                           \
    for (int jj = 0; jj < 2; jj++) {                                            \
        const int cc = w * 2 + jj;                                              \
        const int d_ = cc * 16 + (lane >> 2);                                   \
        const int cl = (lane & 3) ^ ((d_ >> 1) & 3);                            \
        gload_lds16(vt_h + (size_t)d_ * Tn + (kb_) + cl * 8,                    \
                    &Vs[sl_][cc * 512]);                                        \
    } } while (0)

// defer-max softmax over 2 c-blocks (exp2 domain; s includes scale*log2e)
#define SMX(sv, mv, lv, ov, qwx, prow)                                          \
{                                                                               \
    float a_[4][2]; float mxr_[4]; bool ok_ = true;                             \
    _Pragma("unroll")                                                           \
    for (int r = 0; r < 4; r++) {                                               \
        const int qrow = (qwx) + l4 * 4 + r;                                    \
        _Pragma("unroll")                                                       \
        for (int c = 0; c < 2; c++)                                             \
            a_[r][c] = (kb + c * 16 + l15 <= qrow) ? sv[c][r] : -1e30f;         \
        mxr_[r] = fmaxf(a_[r][0], a_[r][1]);                                    \
        ok_ = ok_ && (mxr_[r] <= mv[r] + 8.f);                                  \
    }                                                                           \
    if (__builtin_expect((bool)__all(ok_), 1)) {                                \
        _Pragma("unroll")                                                       \
        for (int r = 0; r < 4; r++) {                                           \
            float rs = 0.f;                                                     \
            _Pragma("unroll")                                                   \
            for (int c = 0; c < 2; c++) {                                       \
                const float e = __builtin_exp2f(a_[r][c] - mv[r]);              \
                rs += e;                                                        \
                Ps[w][(prow) + l4 * 4 + r][c * 16 + l15] = (HT)e;               \
            }                                                                   \
            lv[r] += rs;                                                        \
        }                                                                       \
    } else {                                                                    \
        float al_[4];                                                           \
        _Pragma("unroll")                                                       \
        for (int r = 0; r < 4; r++) {                                           \
            float mx = mxr_[r];                                                 \
            _Pragma("unroll")                                                   \
            for (int sh = 1; sh < 16; sh <<= 1) mx = fmaxf(mx, __shfl_xor(mx, sh)); \
            const float mn = fmaxf(mv[r], mx);                                  \
            al_[r] = __builtin_exp2f(mv[r] - mn);                               \
            mv[r] = mn;                                                         \
            float rs = 0.f;                                                     \
            _Pragma("unroll")                                                   \
            for (int c = 0; c < 2; c++) {                                       \
                const float e = __builtin_exp2f(a_[r][c] - mn);                 \
                rs += e;                                                        \
                Ps[w][(prow) + l4 * 4 + r][c * 16 + l15] = (HT)e;               \
            }                                                                   \
            lv[r] = lv[r] * al_[r] + rs;                                        \
        }                                                                       \
        _Pragma("unroll")                                                       \
        for (int g = 0; g < 8; g++)                                             \
            _Pragma("unroll")                                                   \
            for (int r = 0; r < 4; r++) ov[g][r] *= al_[r];                     \
    }                                                                           \
}

#define KBODY(ACT0)                                                             \
{                                                                               \
    f32x4 s0[2] = {}, s1[2] = {};                                               \
    __builtin_amdgcn_s_setprio(1);                                              \
    _Pragma("unroll")                                                           \
    for (int c = 0; c < 2; c++) {                                               \
        const int kr = c * 16 + l15;                                            \
        const int sw = (kr & 7) << 4;                                           \
        const char* kbase = (const char*)&Ks_n[sl][0] + kr * 256;               \
        const char* rbase = (const char*)&Ks_r[sl][0] + kr * 128;               \
        const h8 br0 = *(const h8*)(rbase + ((l4 * 16) ^ sw));                  \
        const h8 br1 = *(const h8*)(rbase + ((64 + l4 * 16) ^ sw));             \
        _Pragma("unroll")                                                       \
        for (int f = 0; f < 4; f++) {                                           \
            const h8 kf = *(const h8*)(kbase + ((f * 64 + l4 * 16) ^ sw));      \
            s1[c] = mfma16(aq1[f], kf, s1[c]);                                  \
            if (ACT0) s0[c] = mfma16(aq0[f], kf, s0[c]);                        \
        }                                                                       \
        s1[c] = mfma16(aq1[4], br0, s1[c]);                                     \
        s1[c] = mfma16(aq1[5], br1, s1[c]);                                     \
        if (ACT0) { s0[c] = mfma16(aq0[4], br0, s0[c]);                         \
                    s0[c] = mfma16(aq0[5], br1, s0[c]); }                       \
    }                                                                           \
    __builtin_amdgcn_s_setprio(0);                                              \
    SMX(s1, m1v, l1v, o1, qw1, 16);                                             \
    if (ACT0) SMX(s0, m0v, l0v, o0, qw0, 0);                                    \
    const h8 ap1 = *reinterpret_cast<const h8*>(&Ps[w][16 + l15][l4 * 8]);      \
    h8 ap0 = ap1;                                                               \
    if (ACT0) ap0 = *reinterpret_cast<const h8*>(&Ps[w][l15][l4 * 8]);          \
    __builtin_amdgcn_s_setprio(1);                                              \
    _Pragma("unroll")                                                           \
    for (int g = 0; g < 8; g++) {                                               \
        const int d = g * 16 + l15;                                             \
        const int swd = ((d >> 1) & 3) << 4;                                    \
        const char* vbase = (const char*)&Vs[sl][0] + d * 64;                   \
        const h8 v0 = *(const h8*)(vbase + ((l4 * 16) ^ swd));                  \
        o1[g] = mfma16(ap1, v0, o1[g]);                                         \
        if (ACT0) o0[g] = mfma16(ap0, v0, o0[g]);                               \
    }                                                                           \
    __builtin_amdgcn_s_setprio(0);                                              \
}

    const int nkb = (thi + 1) * 2;       // 32-row k-blocks
    STAGE(0, 0);

    for (int t = 0; t < nkb; t++) {
        const int kb = t * 32;
        const int sl = t & 1;
        if (t + 1 < nkb) {
            STAGE(sl ^ 1, kb + 32);
            VWAIT(5);                    // oldest 5 = stage(t) retired
        } else {
            VWAIT(0);
        }
        SBAR();                          // stage(t) visible to all waves
        if (kb <= qw0 + 15)      KBODY(1)
        else if (kb <= qw1 + 15) KBODY(0)
        SBAR();                          // slot-t reads done before overwrite
    }
#undef KBODY
#undef SMX
#undef STAGE

    // final: reduce per-lane partial l across the 16-lane row group, store
    {
        const size_t orow = bT + qw1 + l4 * 4;
        #pragma unroll
        for (int r = 0; r < 4; r++) {
            float rsum = l1v[r];
            #pragma unroll
            for (int sh = 1; sh < 16; sh <<= 1) rsum += __shfl_xor(rsum, sh);
            const float inv = 1.0f / rsum;
            HT* dst = ao + (orow + r) * 2048 + h * 128 + l15;
            #pragma unroll
            for (int g = 0; g < 8; g++) dst[g * 16] = (HT)(o1[g][r] * inv);
        }
    }
    {
        const size_t orow = bT + qw0 + l4 * 4;
        #pragma unroll
        for (int r = 0; r < 4; r++) {
            float rsum = l0v[r];
            #pragma unroll
            for (int sh = 1; sh < 16; sh <<= 1) rsum += __shfl_xor(rsum, sh);
            const float inv = 1.0f / rsum;
            HT* dst = ao + (orow + r) * 2048 + h * 128 + l15;
            #pragma unroll
            for (int g = 0; g < 8; g++) dst[g * 16] = (HT)(o0[g][r] * inv);
        }
    }
}

// ---------------------------------------------------------------------------
extern "C" void kernel_launch(void* const* d_in, const int* in_sizes, int n_in,
                              void* d_out, int out_size, void* d_ws, size_t ws_size,
                              hipStream_t stream)
{
    const float* x     = (const float*)d_in[0];
    const float* w_cq  = (const float*)d_in[1];
    const float* g_q   = (const float*)d_in[2];
    const float* w_ckv = (const float*)d_in[3];
    const float* g_kv  = (const float*)d_in[4];
    const float* w_dqn = (const float*)d_in[5];
    const float* w_dqr = (const float*)d_in[6];
    const float* w_dkn = (const float*)d_in[7];
    const float* w_dv  = (const float*)d_in[8];
    const float* w_kr  = (const float*)d_in[9];
    const float* w_out = (const float*)d_in[10];

    char* ws = (char*)d_ws;
    HT* cqT   = (HT*)(ws + 0);           // [1536][2048]  6,291,456
    HT* ckvT  = (HT*)(ws + 6291456);     // [512][2048]   2,097,152
    HT* krT   = (HT*)(ws + 8388608);     // [64][2048]      262,144
    //  pad region [8650752, 8912896) read as garbage B rows (never written out)
    HT* dqnT  = (HT*)(ws + 8912896);     // [2048][1536]  6,291,456
    HT* dqrT  = (HT*)(ws + 15204352);    // [1024][1536]  3,145,728
    HT* dknT  = (HT*)(ws + 18350080);    // [2048][512]   2,097,152
    HT* dvT   = (HT*)(ws + 20447232);    // [2048][512]   2,097,152
    HT* outT  = (HT*)(ws + 22544384);    // [2048][2048]  8,388,608
    HT* cq    = (HT*)(ws + 30932992);    // [4096][1536] 12,582,912
    HT* ckv   = (HT*)(ws + 43515904);    // [4096][512]   4,194,304
    HT* qn    = (HT*)(ws + 47710208);    // [4096][2048] 16,777,216 (x16/ao alias)
    HT* qr    = (HT*)(ws + 64487424);    // [4096][1024]  8,388,608
    HT* kn    = (HT*)(ws + 72876032);    // [4096][2048] 16,777,216
    HT* kr16  = (HT*)(ws + 89653248);    // [4096][64]      524,288
    HT* vt    = (HT*)(ws + 0);           // [2][16][128][2048] 16,777,216 (alias)
    HT* x16   = qn;
    HT* ao    = qn;

    float* out_o = (float*)d_out;
    float* out_k = out_o + (size_t)BT * Dm;
    float* out_v = out_k + (size_t)2 * Hh * Tn * 192;
    float2* cstab = (float2*)out_v;      // stashed; overwritten after Q GEMM

    const dim3 blk(256);

    // merged prep: cstab + 8x weight transpose + x fp32->fp16
    PrepArgs pa;
    pa.s[0]=w_cq;  pa.d[0]=cqT;  pa.K[0]=2048; pa.N[0]=1536;
    pa.s[1]=w_ckv; pa.d[1]=ckvT; pa.K[1]=2048; pa.N[1]=512;
    pa.s[2]=w_kr;  pa.d[2]=krT;  pa.K[2]=2048; pa.N[2]=64;
    pa.s[3]=w_dqn; pa.d[3]=dqnT; pa.K[3]=1536; pa.N[3]=2048;
    pa.s[4]=w_dqr; pa.d[4]=dqrT; pa.K[4]=1536; pa.N[4]=1024;
    pa.s[5]=w_dkn; pa.d[5]=dknT; pa.K[5]=512;  pa.N[5]=2048;
    pa.s[6]=w_dv;  pa.d[6]=dvT;  pa.K[6]=512;  pa.N[6]=2048;
    pa.s[7]=w_out; pa.d[7]=outT; pa.K[7]=2048; pa.N[7]=2048;
    {
        int acc = 0;
        for (int i = 0; i < 8; i++) {
            pa.start[i] = acc;
            acc += (pa.N[i] >> 6) * (pa.K[i] >> 6);   // total 3744
        }
    }
    pa.cs = cstab; pa.x = x; pa.x16 = x16;
    prep_kernel<<<dim3(8096), blk, 0, stream>>>(pa);

    // fused latent GEMM: N=2176 (cq | ckv | kr16-rope + out_k bcast | pad)
    gemm16d<0><<<dim3(17, BT/128), blk, 0, stream>>>(x16, cqT, Dm,
        cq, ckv, kr16, out_k, nullptr, cstab);

    rmsnorm2_kernel<<<dim3(BT, 2), blk, 0, stream>>>(cq, g_q, ckv, g_kv);

    // fused Q GEMM: N=3072 (qn | qr-rope)  [reads cstab; must precede KV GEMM]
    gemm16d<1><<<dim3(24, BT/128), blk, 0, stream>>>(cq, dqnT, QRc,
        qn, qr, nullptr, nullptr, nullptr, cstab);
    // fused KV GEMM: N=4096 (kn+out_k | vt+out_v)  [overwrites cstab & weights]
    gemm16d<2><<<dim3(32, BT/128), blk, 0, stream>>>(ckv, dknT, KVRc,
        kn, nullptr, vt, out_k, out_v, nullptr);

    // attention (dbuf counted-vmcnt staging + lean softmax + V-conflict fix)
    attn10_kernel<<<dim3(512), blk, 0, stream>>>(qn, qr, kn, kr16, vt, ao);

    // output projection
    gemm16d<3><<<dim3(16, BT/128), blk, 0, stream>>>(ao, outT, Dm,
        nullptr, nullptr, nullptr, out_o, nullptr, nullptr);
}

// Round 15
// 330.501 us; speedup vs baseline: 1.1609x; 1.1609x over previous
//
#include <hip/hip_runtime.h>
#include <cstdint>
#include <cstddef>

typedef _Float16 HT;
typedef _Float16 h8 __attribute__((ext_vector_type(8)));
typedef _Float16 h4 __attribute__((ext_vector_type(4)));
typedef float f32x4 __attribute__((ext_vector_type(4)));

constexpr int Tn  = 2048;
constexpr int Dm  = 2048;
constexpr int Hh  = 16;
constexpr int RDc = 64;
constexpr int QRc = 1536;
constexpr int KVRc= 512;
constexpr int BT  = 4096;

#define VWAIT(N) asm volatile("s_waitcnt vmcnt(" #N ")" ::: "memory")
#define SBAR()   __builtin_amdgcn_s_barrier()

__device__ __forceinline__ f32x4 mfma16(h8 a, h8 b, f32x4 c) {
    return __builtin_amdgcn_mfma_f32_16x16x32_f16(a, b, c, 0, 0, 0);
}
__device__ __forceinline__ void gload_lds16(const void* g, void* l) {
    __builtin_amdgcn_global_load_lds(
        (const __attribute__((address_space(1))) unsigned int*)g,
        (__attribute__((address_space(3))) unsigned int*)l, 16, 0, 0);
}

// ---------------------------------------------------------------------------
// Merged prep kernel: [0,256) cstab | [256,4000) wtrans x8 | [4000,8096) convx
// ---------------------------------------------------------------------------
struct PrepArgs {
    const float* s[8];
    HT* d[8];
    int K[8], N[8], start[8];
    float2* cs;
    const float* x;
    HT* x16;
};

__global__ __launch_bounds__(256)
void prep_kernel(PrepArgs p)
{
    __shared__ float Ts[64][65];
    const int bid = blockIdx.x;
    const int tid = threadIdx.x;

    if (bid < 256) {                      // cstab: 65536 entries
        const int idx = bid * 256 + tid;
        const int t = idx >> 5, i = idx & 31;
        const float ang = (float)t * exp2f(-(float)i * (13.287712379549449f / 32.f));
        p.cs[idx] = make_float2(cosf(ang), sinf(ang));
        return;
    }
    if (bid >= 4000) {                    // convx: fp32 x -> fp16 x16
        const size_t i = ((size_t)(bid - 4000) * 256 + tid) * 8;
        f32x4 a = *reinterpret_cast<const f32x4*>(p.x + i);
        f32x4 b = *reinterpret_cast<const f32x4*>(p.x + i + 4);
        h8 v;
        #pragma unroll
        for (int j = 0; j < 4; j++) { v[j] = (HT)a[j]; v[4 + j] = (HT)b[j]; }
        *reinterpret_cast<h8*>(p.x16 + i) = v;
        return;
    }
    // wtrans: src fp32 [K][N] -> dst fp16 [N][K]
    const int bx0 = bid - 256;
    int seg = 0;
    #pragma unroll
    for (int i = 1; i < 8; i++) if (bx0 >= p.start[i]) seg = i;
    const float* src = p.s[seg];
    HT* dst = p.d[seg];
    const int K = p.K[seg], N = p.N[seg];
    const int bx = bx0 - p.start[seg];
    const int nx = N >> 6;
    const int n0 = (bx % nx) * 64, k0 = (bx / nx) * 64;
    {
        const int r = tid >> 2, c0 = (tid & 3) * 16;
        const float* s = src + (size_t)(k0 + r) * N + n0 + c0;
        #pragma unroll
        for (int j = 0; j < 4; j++)
            *reinterpret_cast<f32x4*>(&Ts[r][c0 + j * 4]) = *reinterpret_cast<const f32x4*>(s + j * 4);
    }
    __syncthreads();
    {
        const int c = tid >> 2, kq = (tid & 3) * 16;
        h8 o0, o1;
        #pragma unroll
        for (int j = 0; j < 8; j++) { o0[j] = (HT)Ts[kq + j][c]; o1[j] = (HT)Ts[kq + 8 + j][c]; }
        HT* d = dst + (size_t)(n0 + c) * K + k0 + kq;
        *reinterpret_cast<h8*>(d)     = o0;
        *reinterpret_cast<h8*>(d + 8) = o1;
    }
}

// ---------------------------------------------------------------------------
// PROVEN R7 GEMM: 128x128 tile, BK=32, 2-slot dbuf, counted vmcnt(4),
// 2-bit XOR LDS swizzle both-sides, 32KB LDS (occupancy-optimal).
// EPI: 0=latent(cq|ckv|kr16-rope) 1=Q(qn|qr-rope) 2=KV(kn+out_k|vt+out_v) 3=OUT
// ---------------------------------------------------------------------------
template<int EPI>
__global__ __launch_bounds__(256)
void gemm16d(const HT* __restrict__ A, const HT* __restrict__ Bt, const int K,
             HT* __restrict__ o1, HT* __restrict__ o2, HT* __restrict__ o3,
             float* __restrict__ f1, float* __restrict__ f2,
             const float2* __restrict__ cstab)
{
    __shared__ HT As[2][4096];
    __shared__ HT Bs[2][4096];

    const int tid  = threadIdx.x;
    const int lane = tid & 63;
    const int l15  = lane & 15, l4 = lane >> 4;
    const int w    = tid >> 6;
    const int wr   = w >> 1, wc = w & 1;
    const int m0   = blockIdx.y * 128;
    const int n0   = blockIdx.x * 128;

    f32x4 acc[4][4] = {};
    const int nk = K >> 5;

    const int schunk = ((lane & 3) ^ ((lane >> 2) & 3) ^ ((lane >> 4) & 3)) * 8;

#define GSTAGE(as_, bs_, kt_) do {                                             \
    _Pragma("unroll")                                                          \
    for (int i_ = 0; i_ < 2; i_++) {                                           \
        const int row_ = (w * 2 + i_) * 16 + (lane >> 2);                      \
        gload_lds16(A  + (size_t)(m0 + row_) * K + (kt_) + schunk,             \
                    (as_) + (w * 2 + i_) * 512);                               \
        gload_lds16(Bt + (size_t)(n0 + row_) * K + (kt_) + schunk,             \
                    (bs_) + (w * 2 + i_) * 512);                               \
    } } while (0)

    GSTAGE(As[0], Bs[0], 0);

    const int sl = (l4 ^ (l15 & 3) ^ ((l15 >> 2) & 3)) * 8;

    for (int kt = 0; kt < nk; kt++) {
        HT* as = As[kt & 1];
        HT* bs = Bs[kt & 1];
        if (kt + 1 < nk) {
            GSTAGE(As[(kt + 1) & 1], Bs[(kt + 1) & 1], (kt + 1) * 32);
            VWAIT(4);
        } else {
            VWAIT(0);
        }
        SBAR();

        h8 af[4], bf[4];
        #pragma unroll
        for (int f = 0; f < 4; f++)
            af[f] = *reinterpret_cast<const h8*>(&as[(wr * 64 + f * 16 + l15) * 32 + sl]);
        #pragma unroll
        for (int g = 0; g < 4; g++)
            bf[g] = *reinterpret_cast<const h8*>(&bs[(wc * 64 + g * 16 + l15) * 32 + sl]);
        #pragma unroll
        for (int f = 0; f < 4; f++)
            #pragma unroll
            for (int g = 0; g < 4; g++)
                acc[f][g] = mfma16(af[f], bf[g], acc[f][g]);
        SBAR();
    }
#undef GSTAGE

    #pragma unroll
    for (int f = 0; f < 4; f++) {
        #pragma unroll
        for (int g = 0; g < 4; g++) {
            const int row = m0 + wr * 64 + f * 16 + l4 * 4;
            const int col = n0 + wc * 64 + g * 16 + l15;
            if constexpr (EPI == 3) {
                #pragma unroll
                for (int r = 0; r < 4; r++)
                    f1[(size_t)(row + r) * 2048 + col] = acc[f][g][r];
            } else if constexpr (EPI == 0) {
                if (col < 1536) {
                    #pragma unroll
                    for (int r = 0; r < 4; r++)
                        o1[(size_t)(row + r) * 1536 + col] = (HT)acc[f][g][r];
                } else if (col < 2048) {
                    #pragma unroll
                    for (int r = 0; r < 4; r++)
                        o2[(size_t)(row + r) * 512 + (col - 1536)] = (HT)acc[f][g][r];
                } else if (col < 2112) {
                    const int cc = col - 2048;
                    const int i = cc >> 1;
                    const bool odd = cc & 1;
                    #pragma unroll
                    for (int r = 0; r < 4; r++) {
                        const int t = (row + r) & (Tn - 1);
                        const float2 cs = cstab[t * 32 + i];
                        const float v = acc[f][g][r];
                        const float p = __shfl_xor(v, 1);
                        const float ov = odd ? p * cs.y + v * cs.x : v * cs.x - p * cs.y;
                        o3[(size_t)(row + r) * 64 + cc] = (HT)ov;
                    }
                }
            } else if constexpr (EPI == 1) {
                if (col < 2048) {
                    #pragma unroll
                    for (int r = 0; r < 4; r++)
                        o1[(size_t)(row + r) * 2048 + col] = (HT)acc[f][g][r];
                } else {
                    const int cc = col - 2048;
                    const int i = (cc & 63) >> 1;
                    const bool odd = cc & 1;
                    #pragma unroll
                    for (int r = 0; r < 4; r++) {
                        const int t = (row + r) & (Tn - 1);
                        const float2 cs = cstab[t * 32 + i];
                        const float v = acc[f][g][r];
                        const float p = __shfl_xor(v, 1);
                        const float ov = odd ? p * cs.y + v * cs.x : v * cs.x - p * cs.y;
                        o2[(size_t)(row + r) * 1024 + cc] = (HT)ov;
                    }
                }
            } else {  // EPI == 2
                if (col < 2048) {
                    const int h = col >> 7, d = col & 127;
                    #pragma unroll
                    for (int r = 0; r < 4; r++) {
                        const int rw = row + r;
                        const int b = rw >> 11, t = rw & (Tn - 1);
                        o1[(size_t)rw * 2048 + col] = (HT)acc[f][g][r];
                        f1[((size_t)(b * Hh + h) * Tn + t) * 192 + d] = acc[f][g][r];
                    }
                } else {
                    const int c2 = col - 2048;
                    const int h = c2 >> 7, d = c2 & 127;
                    const int b = row >> 11, t0 = row & (Tn - 1);
                    h4 pk;
                    #pragma unroll
                    for (int r = 0; r < 4; r++) {
                        f2[((size_t)(b * Hh + h) * Tn + t0 + r) * 128 + d] = acc[f][g][r];
                        pk[r] = (HT)acc[f][g][r];
                    }
                    *reinterpret_cast<h4*>(&o3[((size_t)(b * Hh + h) * 128 + d) * Tn + t0]) = pk;
                }
            }
        }
    }
}

// ---------------------------------------------------------------------------
// broadcast rope slice of out_k across 16 heads (fp32, coalesced f32x4 rows)
// ---------------------------------------------------------------------------
__global__ __launch_bounds__(256)
void kropebc_kernel(const HT* __restrict__ kr16, float* __restrict__ out_k)
{
    const int idx = blockIdx.x * 256 + threadIdx.x;    // 2*2048*16
    const int j4 = (idx & 15) * 4;
    const int t  = (idx >> 4) & (Tn - 1);
    const int b  = idx >> 15;
    h4 v = *reinterpret_cast<const h4*>(&kr16[((size_t)(b * Tn + t)) * 64 + j4]);
    f32x4 f;
    #pragma unroll
    for (int r = 0; r < 4; r++) f[r] = (float)v[r];
    #pragma unroll
    for (int h = 0; h < Hh; h++)
        *reinterpret_cast<f32x4*>(&out_k[((size_t)(b * Hh + h) * Tn + t) * 192 + 128 + j4]) = f;
}

// ---------------------------------------------------------------------------
__global__ __launch_bounds__(256)
void rmsnorm2_kernel(HT* __restrict__ Xa, const float* __restrict__ ga,
                     HT* __restrict__ Xb, const float* __restrict__ gb)
{
    const int which = blockIdx.y;
    HT* X = which ? Xb : Xa;
    const float* g = which ? gb : ga;
    const int N = which ? 512 : 1536;
    const int row = blockIdx.x;
    HT* x = X + (size_t)row * N;
    float ss = 0.f;
    for (int i = threadIdx.x * 8; i < N; i += 2048) {
        h8 v = *reinterpret_cast<const h8*>(&x[i]);
        #pragma unroll
        for (int j = 0; j < 8; j++) { float f = (float)v[j]; ss += f * f; }
    }
    #pragma unroll
    for (int sh = 32; sh >= 1; sh >>= 1) ss += __shfl_xor(ss, sh);
    __shared__ float red[4];
    if ((threadIdx.x & 63) == 0) red[threadIdx.x >> 6] = ss;
    __syncthreads();
    const float tot = red[0] + red[1] + red[2] + red[3];
    const float scale = rsqrtf(tot / (float)N + 1e-6f);
    for (int i = threadIdx.x * 8; i < N; i += 2048) {
        h8 v = *reinterpret_cast<const h8*>(&x[i]);
        f32x4 g0 = *reinterpret_cast<const f32x4*>(&g[i]);
        f32x4 g1 = *reinterpret_cast<const f32x4*>(&g[i + 4]);
        #pragma unroll
        for (int j = 0; j < 4; j++) { v[j]   = (HT)((float)v[j]   * scale * g0[j]);
                                      v[4+j] = (HT)((float)v[4+j] * scale * g1[j]); }
        *reinterpret_cast<h8*>(&x[i]) = v;
    }
}

// ---------------------------------------------------------------------------
// Flash attention v10b: KBLK=32 dbuf counted-vmcnt staging, lean softmax
// (exp2 domain, defer-max THR=8, per-lane partial l), V chunk swizzle
// (d>>1)&3 both sides (2-way banking).
// ---------------------------------------------------------------------------
__global__ __launch_bounds__(256, 2)
void attn10_kernel(const HT* __restrict__ qn, const HT* __restrict__ qr,
                   const HT* __restrict__ kn, const HT* __restrict__ kr16,
                   const HT* __restrict__ vt, HT* __restrict__ ao)
{
    __shared__ HT Ks_n[2][32 * 128];   // 8KB/slot, row=256B, chunk^=(row&7)
    __shared__ HT Ks_r[2][32 * 64];    // 4KB/slot, row=128B, chunk^=(row&7)
    __shared__ HT Vs[2][128 * 32];     // 8KB/slot, row=64B,  chunk^=((d>>1)&3)
    __shared__ HT Ps[4][32][40];       // 10KB

    const int tid  = threadIdx.x;
    const int lane = tid & 63;
    const int l15  = lane & 15, l4 = lane >> 4;
    const int w    = tid >> 6;

    const int bid = blockIdx.x;          // 512
    const int j   = bid >> 5;
    const int h   = bid & 15;
    const int b   = (bid >> 4) & 1;
    const int thi = 31 - j;

    const size_t bT = (size_t)b * Tn;
    const HT* vt_h = vt + ((size_t)(b * Hh + h) * 128) * Tn;

    const int qw0 = j   * 64 + w * 16;
    const int qw1 = thi * 64 + w * 16;

    h8 aq0[6], aq1[6];
    {
        const HT sc = (HT)(0.07216878364870323f * 1.4426950408889634f); // 1/sqrt(192)*log2e
        const size_t rq0 = bT + qw0 + l15;
        const HT* pn = qn + rq0 * 2048 + h * 128 + l4 * 8;
        #pragma unroll
        for (int f = 0; f < 4; f++) aq0[f] = *reinterpret_cast<const h8*>(pn + f * 32) * sc;
        const HT* pr = qr + rq0 * 1024 + h * 64 + l4 * 8;
        aq0[4] = *reinterpret_cast<const h8*>(pr) * sc;
        aq0[5] = *reinterpret_cast<const h8*>(pr + 32) * sc;
        const size_t rq1 = bT + qw1 + l15;
        const HT* pn1 = qn + rq1 * 2048 + h * 128 + l4 * 8;
        #pragma unroll
        for (int f = 0; f < 4; f++) aq1[f] = *reinterpret_cast<const h8*>(pn1 + f * 32) * sc;
        const HT* pr1 = qr + rq1 * 1024 + h * 64 + l4 * 8;
        aq1[4] = *reinterpret_cast<const h8*>(pr1) * sc;
        aq1[5] = *reinterpret_cast<const h8*>(pr1 + 32) * sc;
    }

    f32x4 o0[8] = {}, o1[8] = {};
    float m0v[4] = {-1e30f, -1e30f, -1e30f, -1e30f};
    float m1v[4] = {-1e30f, -1e30f, -1e30f, -1e30f};
    float l0v[4] = {0.f, 0.f, 0.f, 0.f};
    float l1v[4] = {0.f, 0.f, 0.f, 0.f};

// 5 gload_lds chunks per wave: 2 K-nope, 1 K-rope, 2 V
#define STAGE(sl_, kb_) do {                                                    \
    _Pragma("unroll")                                                           \
    for (int jj = 0; jj < 2; jj++) {                                            \
        const int cc = w * 2 + jj;                                              \
        const int r_ = cc * 4 + (lane >> 4);                                    \
        const int cl = (l15 & 8) | ((l15 & 7) ^ (r_ & 7));                      \
        gload_lds16(kn + (bT + (kb_) + r_) * 2048 + h * 128 + cl * 8,           \
                    &Ks_n[sl_][cc * 512]);                                      \
    }                                                                           \
    {                                                                           \
        const int r_ = w * 8 + (lane >> 3);                                     \
        const int cl = (lane & 7) ^ (r_ & 7);                                   \
        gload_lds16(kr16 + (bT + (kb_) + r_) * 64 + cl * 8,                     \
                    &Ks_r[sl_][w * 512]);                                       \
    }                                                                           \
    _Pragma("unroll")                                                           \
    for (int jj = 0; jj < 2; jj++) {                                            \
        const int cc = w * 2 + jj;                                              \
        const int d_ = cc * 16 + (lane >> 2);                                   \
        const int cl = (lane & 3) ^ ((d_ >> 1) & 3);                            \
        gload_lds16(vt_h + (size_t)d_ * Tn + (kb_) + cl * 8,                    \
                    &Vs[sl_][cc * 512]);                                        \
    } } while (0)

// defer-max softmax over 2 c-blocks (exp2 domain; s includes scale*log2e)
#define SMX(sv, mv, lv, ov, qwx, prow)                                          \
{                                                                               \
    float a_[4][2]; float mxr_[4]; bool ok_ = true;                             \
    _Pragma("unroll")                                                           \
    for (int r = 0; r < 4; r++) {                                               \
        const int qrow = (qwx) + l4 * 4 + r;                                    \
        _Pragma("unroll")                                                       \
        for (int c = 0; c < 2; c++)                                             \
            a_[r][c] = (kb + c * 16 + l15 <= qrow) ? sv[c][r] : -1e30f;         \
        mxr_[r] = fmaxf(a_[r][0], a_[r][1]);                                    \
        ok_ = ok_ && (mxr_[r] <= mv[r] + 8.f);                                  \
    }                                                                           \
    if (__builtin_expect((bool)__all(ok_), 1)) {                                \
        _Pragma("unroll")                                                       \
        for (int r = 0; r < 4; r++) {                                           \
            float rs = 0.f;                                                     \
            _Pragma("unroll")                                                   \
            for (int c = 0; c < 2; c++) {                                       \
                const float e = __builtin_exp2f(a_[r][c] - mv[r]);              \
                rs += e;                                                        \
                Ps[w][(prow) + l4 * 4 + r][c * 16 + l15] = (HT)e;               \
            }                                                                   \
            lv[r] += rs;                                                        \
        }                                                                       \
    } else {                                                                    \
        float al_[4];                                                           \
        _Pragma("unroll")                                                       \
        for (int r = 0; r < 4; r++) {                                           \
            float mx = mxr_[r];                                                 \
            _Pragma("unroll")                                                   \
            for (int sh = 1; sh < 16; sh <<= 1) mx = fmaxf(mx, __shfl_xor(mx, sh)); \
            const float mn = fmaxf(mv[r], mx);                                  \
            al_[r] = __builtin_exp2f(mv[r] - mn);                               \
            mv[r] = mn;                                                         \
            float rs = 0.f;                                                     \
            _Pragma("unroll")                                                   \
            for (int c = 0; c < 2; c++) {                                       \
                const float e = __builtin_exp2f(a_[r][c] - mn);                 \
                rs += e;                                                        \
                Ps[w][(prow) + l4 * 4 + r][c * 16 + l15] = (HT)e;               \
            }                                                                   \
            lv[r] = lv[r] * al_[r] + rs;                                        \
        }                                                                       \
        _Pragma("unroll")                                                       \
        for (int g = 0; g < 8; g++)                                             \
            _Pragma("unroll")                                                   \
            for (int r = 0; r < 4; r++) ov[g][r] *= al_[r];                     \
    }                                                                           \
}

#define KBODY(ACT0)                                                             \
{                                                                               \
    f32x4 s0[2] = {}, s1[2] = {};                                               \
    __builtin_amdgcn_s_setprio(1);                                              \
    _Pragma("unroll")                                                           \
    for (int c = 0; c < 2; c++) {                                               \
        const int kr = c * 16 + l15;                                            \
        const int sw = (kr & 7) << 4;                                           \
        const char* kbase = (const char*)&Ks_n[sl][0] + kr * 256;               \
        const char* rbase = (const char*)&Ks_r[sl][0] + kr * 128;               \
        const h8 br0 = *(const h8*)(rbase + ((l4 * 16) ^ sw));                  \
        const h8 br1 = *(const h8*)(rbase + ((64 + l4 * 16) ^ sw));             \
        _Pragma("unroll")                                                       \
        for (int f = 0; f < 4; f++) {                                           \
            const h8 kf = *(const h8*)(kbase + ((f * 64 + l4 * 16) ^ sw));      \
            s1[c] = mfma16(aq1[f], kf, s1[c]);                                  \
            if (ACT0) s0[c] = mfma16(aq0[f], kf, s0[c]);                        \
        }                                                                       \
        s1[c] = mfma16(aq1[4], br0, s1[c]);                                     \
        s1[c] = mfma16(aq1[5], br1, s1[c]);                                     \
        if (ACT0) { s0[c] = mfma16(aq0[4], br0, s0[c]);                         \
                    s0[c] = mfma16(aq0[5], br1, s0[c]); }                       \
    }                                                                           \
    __builtin_amdgcn_s_setprio(0);                                              \
    SMX(s1, m1v, l1v, o1, qw1, 16);                                             \
    if (ACT0) SMX(s0, m0v, l0v, o0, qw0, 0);                                    \
    const h8 ap1 = *reinterpret_cast<const h8*>(&Ps[w][16 + l15][l4 * 8]);      \
    h8 ap0 = ap1;                                                               \
    if (ACT0) ap0 = *reinterpret_cast<const h8*>(&Ps[w][l15][l4 * 8]);          \
    __builtin_amdgcn_s_setprio(1);                                              \
    _Pragma("unroll")                                                           \
    for (int g = 0; g < 8; g++) {                                               \
        const int d = g * 16 + l15;                                             \
        const int swd = ((d >> 1) & 3) << 4;                                    \
        const char* vbase = (const char*)&Vs[sl][0] + d * 64;                   \
        const h8 v0 = *(const h8*)(vbase + ((l4 * 16) ^ swd));                  \
        o1[g] = mfma16(ap1, v0, o1[g]);                                         \
        if (ACT0) o0[g] = mfma16(ap0, v0, o0[g]);                               \
    }                                                                           \
    __builtin_amdgcn_s_setprio(0);                                              \
}

    const int nkb = (thi + 1) * 2;       // 32-row k-blocks
    STAGE(0, 0);

    for (int t = 0; t < nkb; t++) {
        const int kb = t * 32;
        const int sl = t & 1;
        if (t + 1 < nkb) {
            STAGE(sl ^ 1, kb + 32);
            VWAIT(5);                    // oldest 5 = stage(t) retired
        } else {
            VWAIT(0);
        }
        SBAR();                          // stage(t) visible to all waves
        if (kb <= qw0 + 15)      KBODY(1)
        else if (kb <= qw1 + 15) KBODY(0)
        SBAR();                          // slot-t reads done before overwrite
    }
#undef KBODY
#undef SMX
#undef STAGE

    // final: reduce per-lane partial l across the 16-lane row group, store
    {
        const size_t orow = bT + qw1 + l4 * 4;
        #pragma unroll
        for (int r = 0; r < 4; r++) {
            float rsum = l1v[r];
            #pragma unroll
            for (int sh = 1; sh < 16; sh <<= 1) rsum += __shfl_xor(rsum, sh);
            const float inv = 1.0f / rsum;
            HT* dst = ao + (orow + r) * 2048 + h * 128 + l15;
            #pragma unroll
            for (int g = 0; g < 8; g++) dst[g * 16] = (HT)(o1[g][r] * inv);
        }
    }
    {
        const size_t orow = bT + qw0 + l4 * 4;
        #pragma unroll
        for (int r = 0; r < 4; r++) {
            float rsum = l0v[r];
            #pragma unroll
            for (int sh = 1; sh < 16; sh <<= 1) rsum += __shfl_xor(rsum, sh);
            const float inv = 1.0f / rsum;
            HT* dst = ao + (orow + r) * 2048 + h * 128 + l15;
            #pragma unroll
            for (int g = 0; g < 8; g++) dst[g * 16] = (HT)(o0[g][r] * inv);
        }
    }
}

// ---------------------------------------------------------------------------
extern "C" void kernel_launch(void* const* d_in, const int* in_sizes, int n_in,
                              void* d_out, int out_size, void* d_ws, size_t ws_size,
                              hipStream_t stream)
{
    const float* x     = (const float*)d_in[0];
    const float* w_cq  = (const float*)d_in[1];
    const float* g_q   = (const float*)d_in[2];
    const float* w_ckv = (const float*)d_in[3];
    const float* g_kv  = (const float*)d_in[4];
    const float* w_dqn = (const float*)d_in[5];
    const float* w_dqr = (const float*)d_in[6];
    const float* w_dkn = (const float*)d_in[7];
    const float* w_dv  = (const float*)d_in[8];
    const float* w_kr  = (const float*)d_in[9];
    const float* w_out = (const float*)d_in[10];

    char* ws = (char*)d_ws;
    HT* cqT   = (HT*)(ws + 0);           // [1536][2048]  6,291,456
    HT* ckvT  = (HT*)(ws + 6291456);     // [512][2048]   2,097,152
    HT* krT   = (HT*)(ws + 8388608);     // [64][2048]      262,144
    //  pad region [8650752, 8912896) read as garbage B rows (never written out)
    HT* dqnT  = (HT*)(ws + 8912896);     // [2048][1536]  6,291,456
    HT* dqrT  = (HT*)(ws + 15204352);    // [1024][1536]  3,145,728
    HT* dknT  = (HT*)(ws + 18350080);    // [2048][512]   2,097,152
    HT* dvT   = (HT*)(ws + 20447232);    // [2048][512]   2,097,152
    HT* outT  = (HT*)(ws + 22544384);    // [2048][2048]  8,388,608
    HT* cq    = (HT*)(ws + 30932992);    // [4096][1536] 12,582,912
    HT* ckv   = (HT*)(ws + 43515904);    // [4096][512]   4,194,304
    HT* qn    = (HT*)(ws + 47710208);    // [4096][2048] 16,777,216 (x16/ao alias)
    HT* qr    = (HT*)(ws + 64487424);    // [4096][1024]  8,388,608
    HT* kn    = (HT*)(ws + 72876032);    // [4096][2048] 16,777,216
    HT* kr16  = (HT*)(ws + 89653248);    // [4096][64]      524,288
    HT* vt    = (HT*)(ws + 0);           // [2][16][128][2048] 16,777,216 (alias)
    HT* x16   = qn;
    HT* ao    = qn;

    float* out_o = (float*)d_out;
    float* out_k = out_o + (size_t)BT * Dm;
    float* out_v = out_k + (size_t)2 * Hh * Tn * 192;
    float2* cstab = (float2*)out_v;      // stashed; overwritten after Q GEMM

    const dim3 blk(256);

    // merged prep: cstab + 8x weight transpose + x fp32->fp16
    PrepArgs pa;
    pa.s[0]=w_cq;  pa.d[0]=cqT;  pa.K[0]=2048; pa.N[0]=1536;
    pa.s[1]=w_ckv; pa.d[1]=ckvT; pa.K[1]=2048; pa.N[1]=512;
    pa.s[2]=w_kr;  pa.d[2]=krT;  pa.K[2]=2048; pa.N[2]=64;
    pa.s[3]=w_dqn; pa.d[3]=dqnT; pa.K[3]=1536; pa.N[3]=2048;
    pa.s[4]=w_dqr; pa.d[4]=dqrT; pa.K[4]=1536; pa.N[4]=1024;
    pa.s[5]=w_dkn; pa.d[5]=dknT; pa.K[5]=512;  pa.N[5]=2048;
    pa.s[6]=w_dv;  pa.d[6]=dvT;  pa.K[6]=512;  pa.N[6]=2048;
    pa.s[7]=w_out; pa.d[7]=outT; pa.K[7]=2048; pa.N[7]=2048;
    {
        int acc = 0;
        for (int i = 0; i < 8; i++) {
            pa.start[i] = acc;
            acc += (pa.N[i] >> 6) * (pa.K[i] >> 6);   // total 3744
        }
    }
    pa.cs = cstab; pa.x = x; pa.x16 = x16;
    prep_kernel<<<dim3(8096), blk, 0, stream>>>(pa);

    // fused latent GEMM: N=2176 (cq | ckv | kr16-rope | pad)
    gemm16d<0><<<dim3(17, BT/128), blk, 0, stream>>>(x16, cqT, Dm,
        cq, ckv, kr16, nullptr, nullptr, cstab);
    kropebc_kernel<<<dim3(256), blk, 0, stream>>>(kr16, out_k);

    rmsnorm2_kernel<<<dim3(BT, 2), blk, 0, stream>>>(cq, g_q, ckv, g_kv);

    // fused Q GEMM: N=3072 (qn | qr-rope)  [reads cstab; must precede KV GEMM]
    gemm16d<1><<<dim3(24, BT/128), blk, 0, stream>>>(cq, dqnT, QRc,
        qn, qr, nullptr, nullptr, nullptr, cstab);
    // fused KV GEMM: N=4096 (kn+out_k | vt+out_v)  [overwrites cstab & weights]
    gemm16d<2><<<dim3(32, BT/128), blk, 0, stream>>>(ckv, dknT, KVRc,
        kn, nullptr, vt, out_k, out_v, nullptr);

    // attention (dbuf counted-vmcnt staging + lean softmax + V-conflict fix)
    attn10_kernel<<<dim3(512), blk, 0, stream>>>(qn, qr, kn, kr16, vt, ao);

    // output projection
    gemm16d<3><<<dim3(16, BT/128), blk, 0, stream>>>(ao, outT, Dm,
        nullptr, nullptr, nullptr, out_o, nullptr, nullptr);
}